// Round 5
// baseline (132.920 us; speedup 1.0000x reference)
//
#include <hip/hip_runtime.h>
#include <hip/hip_fp16.h>

// SuppLayer: out[b,c] = exp( sum_s x[b, cm[c,s]] * w[c,s] )
// B=4096, NCLASS=1000, NSUPP=64, NCHUNK=4096.
//
// R14: R13's VMEM-free-gather schedule, scratch-proof codegen.
//  R13 counters showed VGPR=64 + 29 MB extra WRITE traffic: the cw/wv/hv
//  register arrays were passed by pointer into helpers, defeating SROA ->
//  everything "register-resident" actually lived in scratch (+8 us).
//  Fix: all hot state is NAMED registers (cw0..7, wv0..7, float2 a0..a3),
//  gather passes are macro-expanded, half unpack via union (no
//  address-of-local), hv reduced to 16 floats by streaming the hi rows in
//  two chunks. Peak live set ~105 VGPR < 128 cap of (1024,4).
//  Schedule per block (16 rows, 128 KB LDS, 1 block/CU):
//    preload cw(sg0..7) -> stage lo rows -> bar ->
//    issue hvA (16 loads) -> pass1a accl+=sg0..3@tlo (pure LDS/VALU)
//    cvt A->thi ; issue hvB -> pass1b accl+=sg4..7@tlo ; cvt B->thi
//    load cw(sg8..15) -> bar ->
//    pass2 accl+=sg8..15@tlo -> store lo
//    pass3 acch+=sg8..15@thi -> reload cw(sg0..7)
//    pass4 acch+=sg0..7@thi  -> store hi
//  vmcnt discipline: during each gather pass the outstanding VMEM is only
//  the x-chunk stream (or nothing); no wait touches it until its cvt.
//  Slot = 16 B = 8 rows fp16; read quad = idx&7; pre-pass counting-sorts
//  by (idx-c)&7 so a wave's 64 consecutive classes cycle all 8 quads.

constexpr int B_       = 4096;
constexpr int NCLASS_  = 1000;
constexpr int NSUPP_   = 64;
constexpr int NCHUNK_  = 4096;
constexpr int BT       = 16;     // batch rows per block
constexpr int BH       = BT / 2; // rows per half-tile
constexpr int THREADS_ = 1024;
constexpr int SG_      = NSUPP_ / 4;            // 16 int4/float4 groups
constexpr int SGH_     = SG_ / 2;               // 8 groups resident at a time
constexpr size_t CMT_BYTES = (size_t)SG_ * NCLASS_ * 16;   // 256 KB
constexpr size_t WS_NEEDED = 2 * CMT_BYTES;                // 512 KB

// ---- pre-pass: one wave per class. Sort 64 (idx,w) by key=(idx-c)&7 and
// write to [sg][class] transposed layout. All-register rank computation. ----
__global__ __launch_bounds__(256)
void build_cw_kernel(const int*   __restrict__ cm,
                     const float* __restrict__ w,
                     int*         __restrict__ cmT,
                     float*       __restrict__ wT)
{
    const int t    = threadIdx.x;
    const int c    = blockIdx.x * 4 + (t >> 6);   // 4 classes per block
    const int lane = t & 63;
    if (c >= NCLASS_) return;                      // grid=250 -> never taken

    const int   idx = cm[c * NSUPP_ + lane];
    const float wv  = w [c * NSUPP_ + lane];
    const int   key = (idx - c) & 7;               // read quad = idx&7

    // stable rank of this element in sorted-by-key order
    const unsigned long long below = ((unsigned long long)1 << lane) - 1ull;
    int j = 0;
    #pragma unroll
    for (int r = 0; r < 8; ++r) {
        const unsigned long long m = __ballot(key == r);
        if (key > r)  j += __popcll(m);
        if (key == r) j += __popcll(m & below);
    }

    const int dst = ((j >> 2) * NCLASS_ + c) * 4 + (j & 3);
    cmT[dst] = idx;
    wT [dst] = wv;
}

// fp16x2 (packed in a float) -> float2, without address-of-local
static __device__ __forceinline__ float2 hx2f(const float u) {
    union U { float f; __half2 h; } uu;
    uu.f = u;
    return __half22float2(uu.h);
}

// one support: slot float4 d (8 rows fp16), scalar weight wc, acc a0..a3
#define SUPP_FMA(dc, wc, A) {                          \
    const float2 f_ = hx2f(dc);                        \
    (A).x = fmaf(f_.x, (wc), (A).x);                   \
    (A).y = fmaf(f_.y, (wc), (A).y); }

#define GATHER_ONE(d, wc)                              \
    SUPP_FMA((d).x, (wc), a0)                          \
    SUPP_FMA((d).y, (wc), a1)                          \
    SUPP_FMA((d).z, (wc), a2)                          \
    SUPP_FMA((d).w, (wc), a3)

// one sg group: 4 ds_read_b128 issued up front, then 32 fma
#define GATHER_SG(t4, ci, wf) {                        \
    const float4 d0_ = (t4)[(ci).x];                   \
    const float4 d1_ = (t4)[(ci).y];                   \
    const float4 d2_ = (t4)[(ci).z];                   \
    const float4 d3_ = (t4)[(ci).w];                   \
    GATHER_ONE(d0_, (wf).x)                            \
    GATHER_ONE(d1_, (wf).y)                            \
    GATHER_ONE(d2_, (wf).z)                            \
    GATHER_ONE(d3_, (wf).w) }

#define GATHER_Q0(t4)                                  \
    GATHER_SG(t4, cw0, wv0) GATHER_SG(t4, cw1, wv1)    \
    GATHER_SG(t4, cw2, wv2) GATHER_SG(t4, cw3, wv3)
#define GATHER_Q1(t4)                                  \
    GATHER_SG(t4, cw4, wv4) GATHER_SG(t4, cw5, wv5)    \
    GATHER_SG(t4, cw6, wv6) GATHER_SG(t4, cw7, wv7)

#define LOAD_CW_G(I, H)                                                      \
    if constexpr (USET) {                                                    \
        cw##I = cmT[((H) * SGH_ + I) * NCLASS_ + c];                         \
        wv##I = wT [((H) * SGH_ + I) * NCLASS_ + c];                         \
    } else {                                                                 \
        cw##I = reinterpret_cast<const int4*>(cmap + c * NSUPP_)[(H) * SGH_ + I];   \
        wv##I = reinterpret_cast<const float4*>(wSupp + c * NSUPP_)[(H) * SGH_ + I];\
    }
#define LOAD_CW_HALF(H)                                \
    LOAD_CW_G(0, H) LOAD_CW_G(1, H) LOAD_CW_G(2, H)    \
    LOAD_CW_G(3, H) LOAD_CW_G(4, H) LOAD_CW_G(5, H)    \
    LOAD_CW_G(6, H) LOAD_CW_G(7, H)

template <bool USET>
__global__ __launch_bounds__(THREADS_, 4)
void supp_gather_kernel(const float* __restrict__ x,
                        const float* __restrict__ wSupp,
                        const int*   __restrict__ cmap,
                        const float4* __restrict__ wT,
                        const int4*   __restrict__ cmT,
                        float*       __restrict__ out)
{
    // two 64 KB halves; slot idx = 16 B = 8 rows as half2 pairs
    __shared__ __align__(16) __half2 tile[NCHUNK_ * 8];
    __half2* tlo = tile;
    __half2* thi = tile + NCHUNK_ * 4;
    const float4* tlo4 = reinterpret_cast<const float4*>(tlo);
    const float4* thi4 = reinterpret_cast<const float4*>(thi);

    const int t  = threadIdx.x;
    const int rb = blockIdx.x * BT;   // first batch row of this tile
    const int c  = t;                 // class (t < NCLASS_ only)

    // ---- named register-resident cm/w (8 int4 + 8 float4 = 64 VGPR) ----
    int4   cw0, cw1, cw2, cw3, cw4, cw5, cw6, cw7;
    float4 wv0, wv1, wv2, wv3, wv4, wv5, wv6, wv7;
    if (t < NCLASS_) { LOAD_CW_HALF(0) }

    // ---- phase 1: stage rows rb..rb+7 -> fp16 -> tlo ----
    #pragma unroll
    for (int p = 0; p < NCHUNK_ / THREADS_; ++p) {
        const int col = t + THREADS_ * p;
        float v[BH];
        #pragma unroll
        for (int bi = 0; bi < BH; ++bi)
            v[bi] = x[(size_t)(rb + bi) * NCHUNK_ + col];
        __half2 h2v[BH / 2];
        #pragma unroll
        for (int k = 0; k < BH / 2; ++k)
            h2v[k] = __floats2half2_rn(v[2 * k], v[2 * k + 1]);
        *reinterpret_cast<float4*>(&tlo[(size_t)col * 4]) =
            *reinterpret_cast<const float4*>(&h2v[0]);
    }
    __syncthreads();

    float2 a0 = {0.f, 0.f}, a1 = {0.f, 0.f}, a2 = {0.f, 0.f}, a3 = {0.f, 0.f};
    float hv[16];

    // ---- chunk A: issue 16 hi-row loads (only outstanding VMEM) ----
    #pragma unroll
    for (int p = 0; p < 2; ++p) {
        const int col = t + THREADS_ * p;
        #pragma unroll
        for (int bi = 0; bi < BH; ++bi)
            hv[p * BH + bi] = x[(size_t)(rb + BH + bi) * NCHUNK_ + col];
    }
    __builtin_amdgcn_sched_barrier(0);

    // pass 1a: accl += sg0..3 @ tlo (pure LDS+VALU; chunk A streams under)
    if (t < NCLASS_) { GATHER_Q0(tlo4) }

    // cvt chunk A -> thi (counted vmcnt wait on A only)
    #pragma unroll
    for (int p = 0; p < 2; ++p) {
        const int col = t + THREADS_ * p;
        __half2 h2v[BH / 2];
        #pragma unroll
        for (int k = 0; k < BH / 2; ++k)
            h2v[k] = __floats2half2_rn(hv[p * BH + 2 * k], hv[p * BH + 2 * k + 1]);
        *reinterpret_cast<float4*>(&thi[(size_t)col * 4]) =
            *reinterpret_cast<const float4*>(&h2v[0]);
    }

    // ---- chunk B: issue remaining 16 hi-row loads ----
    #pragma unroll
    for (int p = 0; p < 2; ++p) {
        const int col = t + THREADS_ * (2 + p);
        #pragma unroll
        for (int bi = 0; bi < BH; ++bi)
            hv[p * BH + bi] = x[(size_t)(rb + BH + bi) * NCHUNK_ + col];
    }
    __builtin_amdgcn_sched_barrier(0);

    // pass 1b: accl += sg4..7 @ tlo
    if (t < NCLASS_) { GATHER_Q1(tlo4) }

    // cvt chunk B -> thi
    #pragma unroll
    for (int p = 0; p < 2; ++p) {
        const int col = t + THREADS_ * (2 + p);
        __half2 h2v[BH / 2];
        #pragma unroll
        for (int k = 0; k < BH / 2; ++k)
            h2v[k] = __floats2half2_rn(hv[p * BH + 2 * k], hv[p * BH + 2 * k + 1]);
        *reinterpret_cast<float4*>(&thi[(size_t)col * 4]) =
            *reinterpret_cast<const float4*>(&h2v[0]);
    }

    // swap in cm/w for sg 8..15 (L2-resident)
    if (t < NCLASS_) { LOAD_CW_HALF(1) }
    __syncthreads();

    if (t < NCLASS_) {
        // ---- pass 2: accl += sg8..15 @ tlo -> lo rows complete, store ----
        GATHER_Q0(tlo4)
        GATHER_Q1(tlo4)
        out[(size_t)(rb + 0) * NCLASS_ + c] = __expf(a0.x);
        out[(size_t)(rb + 1) * NCLASS_ + c] = __expf(a0.y);
        out[(size_t)(rb + 2) * NCLASS_ + c] = __expf(a1.x);
        out[(size_t)(rb + 3) * NCLASS_ + c] = __expf(a1.y);
        out[(size_t)(rb + 4) * NCLASS_ + c] = __expf(a2.x);
        out[(size_t)(rb + 5) * NCLASS_ + c] = __expf(a2.y);
        out[(size_t)(rb + 6) * NCLASS_ + c] = __expf(a3.x);
        out[(size_t)(rb + 7) * NCLASS_ + c] = __expf(a3.y);

        // ---- pass 3: acch += sg8..15 @ thi (reuses resident cm/w) ----
        a0 = {0.f, 0.f}; a1 = {0.f, 0.f}; a2 = {0.f, 0.f}; a3 = {0.f, 0.f};
        GATHER_Q0(thi4)
        GATHER_Q1(thi4)

        // ---- pass 4: reload sg0..7, acch += sg0..7 @ thi, store hi ----
        LOAD_CW_HALF(0)
        GATHER_Q0(thi4)
        GATHER_Q1(thi4)
        out[(size_t)(rb +  8) * NCLASS_ + c] = __expf(a0.x);
        out[(size_t)(rb +  9) * NCLASS_ + c] = __expf(a0.y);
        out[(size_t)(rb + 10) * NCLASS_ + c] = __expf(a1.x);
        out[(size_t)(rb + 11) * NCLASS_ + c] = __expf(a1.y);
        out[(size_t)(rb + 12) * NCLASS_ + c] = __expf(a2.x);
        out[(size_t)(rb + 13) * NCLASS_ + c] = __expf(a2.y);
        out[(size_t)(rb + 14) * NCLASS_ + c] = __expf(a3.x);
        out[(size_t)(rb + 15) * NCLASS_ + c] = __expf(a3.y);
    }
}

extern "C" void kernel_launch(void* const* d_in, const int* in_sizes, int n_in,
                              void* d_out, int out_size, void* d_ws, size_t ws_size,
                              hipStream_t stream) {
    const float* x  = (const float*)d_in[0];   // (B, NCHUNK) fp32
    const float* w  = (const float*)d_in[1];   // (NCLASS, NSUPP) fp32
    const int*   cm = (const int*)d_in[2];     // (NCLASS, NSUPP) int32
    float*       o  = (float*)d_out;           // (B, NCLASS) fp32

    int*   cmT = (int*)d_ws;
    float* wT  = (float*)((char*)d_ws + CMT_BYTES);

    const dim3 grid(B_ / BT);                  // 256 blocks, 1 per CU
    if (ws_size >= WS_NEEDED) {
        build_cw_kernel<<<dim3((NCLASS_ + 3) / 4), dim3(256), 0, stream>>>(
            cm, w, cmT, wT);
        supp_gather_kernel<true><<<grid, dim3(THREADS_), 0, stream>>>(
            x, w, cm, (const float4*)wT, (const int4*)cmT, o);
    } else {
        supp_gather_kernel<false><<<grid, dim3(THREADS_), 0, stream>>>(
            x, w, cm, (const float4*)wT, (const int4*)cmT, o);
    }
}